// Round 1
// baseline (736.393 us; speedup 1.0000x reference)
//
#include <hip/hip_runtime.h>
#include <math.h>

// Encoding (deep-TEN style) fused kernel for MI355X.
// x:(B,C,H,W) fp32, codewords:(K,C), scale:(K) -> enc:(B,K,C)
//
// Strategy: read x ONCE. Each block stages a 64-position x-tile (all 512
// channels) into LDS, computes xc = x·cw^T (lanes->n), softmax over K in
// LDS, then aggregates enc[k][c] += aw[n][k]*x[n][c] (lanes->c) into
// persistent VGPR accumulators. The -sum(aw)*cw term is folded in per
// block; one atomicAdd per (k,c) per block into zeroed d_out.

namespace {
constexpr int Bc = 16;
constexpr int Cc = 512;
constexpr int Nc = 9216;   // 96*96
constexpr int Kc = 32;
constexpr int TN = 64;     // positions per tile
constexpr int XPAD = 66;   // x_lds row stride (floats): 2-way conflicts phase A, 4-way phase B
constexpr int APAD = 36;   // aw_lds row stride (floats): keeps float4 alignment (36*4 % 16 == 0)
constexpr int TPG = 9;     // tiles per block: 144 tiles/batch / 16 groups
}

__launch_bounds__(256, 1)
__global__ void enc_main(const float* __restrict__ x,
                         const float* __restrict__ cw,
                         const float* __restrict__ scale,
                         float* __restrict__ out)
{
    __shared__ __attribute__((aligned(16))) float x_lds[Cc * XPAD];   // 135168 B
    __shared__ __attribute__((aligned(16))) float aw_lds[TN * APAD];  // 9216 B
    __shared__ float c2_lds[Kc];
    __shared__ float awp_lds[4][Kc];   // per-wave awsum partials

    const int tid  = threadIdx.x;
    const int lane = tid & 63;
    const int wave = __builtin_amdgcn_readfirstlane(tid >> 6);

    const int b   = blockIdx.x >> 4;   // batch
    const int grp = blockIdx.x & 15;   // tile group within batch

    const float* __restrict__ xb = x + (size_t)b * Cc * Nc;

    // ||c_k||^2, once per block (wave 0)
    if (tid < Kc) {
        const float* r = cw + tid * Cc;
        float s = 0.f;
        for (int c = 0; c < Cc; ++c) { const float v = r[c]; s = fmaf(v, v, s); }
        c2_lds[tid] = s;
    }

    // persistent accumulators: enc[k] for channels c0=tid and c1=tid+256
    float enc0[Kc], enc1[Kc];
    #pragma unroll
    for (int k = 0; k < Kc; ++k) { enc0[k] = 0.f; enc1[k] = 0.f; }
    float awacc[8];
    #pragma unroll
    for (int i = 0; i < 8; ++i) awacc[i] = 0.f;

    const int kb   = wave * 8;     // phase-A k-base for this wave
    const int n_sm = tid >> 2;     // softmax: this thread's n
    const int kq   = tid & 3;      // softmax: this thread's k-octet

    for (int t = 0; t < TPG; ++t) {
        const int n0 = (grp * TPG + t) * TN;
        __syncthreads();   // x_lds free (prev tile's readers done)

        // ---- stage x tile: 512 rows x 64 floats, float2 per thread ----
        {
            const int n2    = (tid & 31) * 2;
            const int cbase = tid >> 5;          // 0..7
            #pragma unroll 8
            for (int i = 0; i < 64; ++i) {
                const int c = cbase + 8 * i;
                const float2 v = *(const float2*)(xb + c * Nc + n0 + n2);
                *(float2*)(&x_lds[c * XPAD + n2]) = v;
            }
        }
        __syncthreads();

        // ---- phase A: xc[n=lane][k=kb..kb+7], codewords via scalar loads ----
        float x2v = 0.f;
        {
            float xc[8];
            #pragma unroll
            for (int q = 0; q < 8; ++q) xc[q] = 0.f;
            #pragma unroll 4
            for (int c = 0; c < Cc; ++c) {
                const float xv = x_lds[c * XPAD + lane];
                x2v = fmaf(xv, xv, x2v);
                #pragma unroll
                for (int q = 0; q < 8; ++q)
                    xc[q] = fmaf(xv, cw[(kb + q) * Cc + c], xc[q]);
            }
            *(float4*)(&aw_lds[lane * APAD + kb])     = make_float4(xc[0], xc[1], xc[2], xc[3]);
            *(float4*)(&aw_lds[lane * APAD + kb + 4]) = make_float4(xc[4], xc[5], xc[6], xc[7]);
        }
        __syncthreads();

        // ---- softmax over K=32: thread -> (n = tid>>2, 8 k's) ----
        {
            const float x2n = __shfl(x2v, n_sm, 64);  // x2 for n lives in lane n of every wave
            const float4 v0 = *(const float4*)(&aw_lds[n_sm * APAD + kq * 8]);
            const float4 v1 = *(const float4*)(&aw_lds[n_sm * APAD + kq * 8 + 4]);
            const float xcv[8] = {v0.x, v0.y, v0.z, v0.w, v1.x, v1.y, v1.z, v1.w};
            float l[8];
            #pragma unroll
            for (int i = 0; i < 8; ++i) {
                const int k = kq * 8 + i;
                l[i] = scale[k] * (x2n - 2.f * xcv[i] + c2_lds[k]);
            }
            float m = l[0];
            #pragma unroll
            for (int i = 1; i < 8; ++i) m = fmaxf(m, l[i]);
            m = fmaxf(m, __shfl_xor(m, 1));   // quad 4n..4n+3 holds all 32 k of n
            m = fmaxf(m, __shfl_xor(m, 2));
            float e[8];
            float s = 0.f;
            #pragma unroll
            for (int i = 0; i < 8; ++i) { e[i] = __expf(l[i] - m); s += e[i]; }
            s += __shfl_xor(s, 1);
            s += __shfl_xor(s, 2);
            const float r = 1.f / s;
            #pragma unroll
            for (int i = 0; i < 8; ++i) { e[i] *= r; awacc[i] += e[i]; }
            *(float4*)(&aw_lds[n_sm * APAD + kq * 8])     = make_float4(e[0], e[1], e[2], e[3]);
            *(float4*)(&aw_lds[n_sm * APAD + kq * 8 + 4]) = make_float4(e[4], e[5], e[6], e[7]);
        }
        __syncthreads();

        // ---- phase B: enc[k][c] += aw[n][k] * x[n][c], lanes->c ----
        {
            const int c0 = tid, c1 = tid + 256;
            const float4* awv = (const float4*)aw_lds;
            #pragma unroll 2
            for (int n = 0; n < TN; ++n) {
                const float xv0 = x_lds[c0 * XPAD + n];
                const float xv1 = x_lds[c1 * XPAD + n];
                #pragma unroll
                for (int q = 0; q < 8; ++q) {
                    const float4 a = awv[n * (APAD / 4) + q];
                    enc0[4*q+0] = fmaf(a.x, xv0, enc0[4*q+0]);
                    enc0[4*q+1] = fmaf(a.y, xv0, enc0[4*q+1]);
                    enc0[4*q+2] = fmaf(a.z, xv0, enc0[4*q+2]);
                    enc0[4*q+3] = fmaf(a.w, xv0, enc0[4*q+3]);
                    enc1[4*q+0] = fmaf(a.x, xv1, enc1[4*q+0]);
                    enc1[4*q+1] = fmaf(a.y, xv1, enc1[4*q+1]);
                    enc1[4*q+2] = fmaf(a.z, xv1, enc1[4*q+2]);
                    enc1[4*q+3] = fmaf(a.w, xv1, enc1[4*q+3]);
                }
            }
        }
    }

    // ---- block awsum[k]: reduce awacc across threads with same kq ----
    #pragma unroll
    for (int i = 0; i < 8; ++i) {
        float v = awacc[i];
        v += __shfl_xor(v, 4);
        v += __shfl_xor(v, 8);
        v += __shfl_xor(v, 16);
        v += __shfl_xor(v, 32);
        awacc[i] = v;   // lanes 0..3 hold per-wave totals for k = lane*8+i
    }
    if (lane < 4) {
        #pragma unroll
        for (int i = 0; i < 8; ++i) awp_lds[wave][lane * 8 + i] = awacc[i];
    }
    __syncthreads();
    if (tid < Kc) {
        awp_lds[0][tid] = awp_lds[0][tid] + awp_lds[1][tid] + awp_lds[2][tid] + awp_lds[3][tid];
    }
    __syncthreads();

    // ---- fold -awsum*cw into partials, then one atomicAdd per (k,c) ----
    float* ob = out + (size_t)b * Kc * Cc;
    #pragma unroll
    for (int k = 0; k < Kc; ++k) {
        const float s = awp_lds[0][k];
        const float p0 = fmaf(-s, cw[k * Cc + tid],       enc0[k]);
        const float p1 = fmaf(-s, cw[k * Cc + tid + 256], enc1[k]);
        atomicAdd(&ob[k * Cc + tid],       p0);
        atomicAdd(&ob[k * Cc + tid + 256], p1);
    }
}

extern "C" void kernel_launch(void* const* d_in, const int* in_sizes, int n_in,
                              void* d_out, int out_size, void* d_ws, size_t ws_size,
                              hipStream_t stream) {
    const float* x     = (const float*)d_in[0];
    const float* cwp   = (const float*)d_in[1];
    const float* scale = (const float*)d_in[2];
    float* out = (float*)d_out;

    hipMemsetAsync(out, 0, (size_t)out_size * sizeof(float), stream);
    enc_main<<<dim3(Bc * 16), dim3(256), 0, stream>>>(x, cwp, scale, out);
}

// Round 2
// 447.446 us; speedup vs baseline: 1.6458x; 1.6458x over previous
//
#include <hip/hip_runtime.h>
#include <hip/hip_bf16.h>

// Encoding (deep-TEN) fused MFMA kernel for MI355X (gfx950).
// x:(B,C,H,W) fp32, codewords:(K,C) fp32, scale:(K) -> enc:(B,K,C) fp32
//
// Per block (b, grp): 9 tiles of 64 positions.
//   matmul1 XC^T[k][n] = CW·X : B-frags loaded DIRECT from global (lane ->
//     (n = lane&15, c-oct = lane>>4)), A-frags from cw_lds (bf16). The same
//     packed bf16 dwords are written to x_cp LDS (c-pair-interleaved layout)
//     for matmul2. x2[n] accumulated from the fp32 staging values in-reg.
//   softmax over K=32 entirely in registers (C-layout + xor-shfl 16/32);
//     aw -> aw_lds[k][n] bf16.
//   matmul2 ENC[k][c] = AW^T·X^T : A-frags from aw_lds, B-frags from x_cp
//     (2x b128 + parity extract), 64 persistent fp32 accumulators/lane.
//   Epilogue: block awsum[k] (shfl + LDS atomic), fold -awsum*cw, one
//     atomicAdd per (k,c) per block into zeroed d_out.

typedef float  f32x4  __attribute__((ext_vector_type(4)));
typedef short  bf16x8 __attribute__((ext_vector_type(8)));

namespace {
constexpr int Cc  = 512;
constexpr int Nc  = 9216;   // 96*96
constexpr int Kc  = 32;
constexpr int TN  = 64;     // positions per tile
constexpr int TPG = 9;      // tiles per block (144 tiles / 16 groups)
constexpr int XROW = 68;    // u32 per c-pair row in x_cp (272 B, 16B-aligned, bank-clean)
constexpr int SKH  = 520;   // cw_lds halfwords per row (1040 B, 16B-aligned)
constexpr int SAH  = 72;    // aw_lds halfwords per row (144 B, 16B-aligned)
}

static __device__ inline unsigned short f2bf(float f) {
    unsigned int u = __float_as_uint(f);
    u += 0x7fffu + ((u >> 16) & 1u);      // RNE (finite inputs)
    return (unsigned short)(u >> 16);
}
static __device__ inline unsigned int pack_bf16(float a, float b) {
    return (unsigned int)f2bf(a) | ((unsigned int)f2bf(b) << 16);
}
static __device__ inline bf16x8 u4_frag(uint4 d) {
    union { uint4 u; bf16x8 v; } cv; cv.u = d; return cv.v;
}

__launch_bounds__(256, 1)
__global__ void enc_mfma(const float* __restrict__ x,
                         const float* __restrict__ cw,
                         const float* __restrict__ scale,
                         float* __restrict__ out)
{
    __shared__ __attribute__((aligned(16))) unsigned int   x_cp[256 * XROW];  // 69632 B
    __shared__ __attribute__((aligned(16))) unsigned short cw_lds[Kc * SKH];  // 33280 B
    __shared__ __attribute__((aligned(16))) unsigned short aw_lds[Kc * SAH];  //  4608 B
    __shared__ float c2p[Kc][8];
    __shared__ float c2_lds[Kc];
    __shared__ float sc_lds[Kc];
    __shared__ float awsum[Kc];

    const int tid  = threadIdx.x;
    const int w    = tid >> 6;          // wave 0..3
    const int nloc = tid & 15;          // fragment row/col lane bits
    const int g    = (tid >> 4) & 3;    // fragment quad

    const int b   = blockIdx.x >> 4;
    const int grp = blockIdx.x & 15;
    const float* __restrict__ xb = x + (size_t)b * Cc * Nc;

    // ---- one-time: codewords -> LDS bf16; c2; scale ----
    for (int i = 0; i < 64; ++i) {
        int flat = tid + 256 * i;                     // 32*512 = 16384
        cw_lds[(flat >> 9) * SKH + (flat & 511)] = f2bf(cw[flat]);
    }
    {
        int k = tid >> 3, seg = tid & 7;
        const float* r = cw + k * Cc + seg * 64;
        float s = 0.f;
        for (int c = 0; c < 64; ++c) s = fmaf(r[c], r[c], s);
        c2p[k][seg] = s;
    }
    if (tid < Kc) { sc_lds[tid] = scale[tid]; awsum[tid] = 0.f; }
    __syncthreads();
    if (tid < Kc) {
        float s = 0.f;
        #pragma unroll
        for (int j = 0; j < 8; ++j) s += c2p[tid][j];
        c2_lds[tid] = s;
    }
    __syncthreads();

    // per-lane k constants: k = 16*t + 4*g + r  (MFMA C-layout rows)
    float sc8[8], c28[8];
    #pragma unroll
    for (int i = 0; i < 8; ++i) {
        int k = 16 * (i >> 2) + 4 * g + (i & 3);
        sc8[i] = sc_lds[k];
        c28[i] = c2_lds[k];
    }

    f32x4 acc2[2][8];
    #pragma unroll
    for (int t = 0; t < 2; ++t)
        #pragma unroll
        for (int ct = 0; ct < 8; ++ct) acc2[t][ct] = (f32x4)0.f;
    float awacc[8] = {0.f,0.f,0.f,0.f,0.f,0.f,0.f,0.f};

    for (int tile = 0; tile < TPG; ++tile) {
        const int n0 = (grp * TPG + tile) * TN;
        const int nw = n0 + 16 * w;      // this wave's 16-n slice

        f32x4 acc1[2];
        acc1[0] = (f32x4)0.f; acc1[1] = (f32x4)0.f;
        float x2 = 0.f;

        __syncthreads();   // x_cp/aw_lds free (prev tile's matmul2 done)

        // ---- staging + matmul1, fused: 16 c-steps of 32 ----
        #pragma unroll 4
        for (int cs = 0; cs < 16; ++cs) {
            const float* p = xb + (size_t)(cs * 32 + g * 8) * Nc + nw + nloc;
            float v[8];
            #pragma unroll
            for (int j = 0; j < 8; ++j) v[j] = p[(size_t)j * Nc];
            unsigned int pk[4];
            #pragma unroll
            for (int j2 = 0; j2 < 4; ++j2) {
                x2 = fmaf(v[2*j2],   v[2*j2],   x2);
                x2 = fmaf(v[2*j2+1], v[2*j2+1], x2);
                pk[j2] = pack_bf16(v[2*j2], v[2*j2+1]);
                x_cp[(cs * 16 + g * 4 + j2) * XROW + 16 * w + nloc] = pk[j2];
            }
            bf16x8 bfrag = u4_frag(make_uint4(pk[0], pk[1], pk[2], pk[3]));
            #pragma unroll
            for (int t = 0; t < 2; ++t) {
                uint4 a = *(const uint4*)&cw_lds[(16*t + nloc) * SKH + cs*32 + g*8];
                acc1[t] = __builtin_amdgcn_mfma_f32_16x16x32_bf16(
                              u4_frag(a), bfrag, acc1[t], 0, 0, 0);
            }
        }

        // ---- softmax over K=32, in registers ----
        x2 += __shfl_xor(x2, 16);
        x2 += __shfl_xor(x2, 32);
        float l[8], aw[8];
        float m = -1e30f;
        #pragma unroll
        for (int i = 0; i < 8; ++i) {
            float xc = acc1[i >> 2][i & 3];
            l[i] = sc8[i] * (x2 - 2.f * xc + c28[i]);
            m = fmaxf(m, l[i]);
        }
        m = fmaxf(m, __shfl_xor(m, 16));
        m = fmaxf(m, __shfl_xor(m, 32));
        float s = 0.f;
        #pragma unroll
        for (int i = 0; i < 8; ++i) { aw[i] = __expf(l[i] - m); s += aw[i]; }
        s += __shfl_xor(s, 16);
        s += __shfl_xor(s, 32);
        const float inv = 1.f / s;
        #pragma unroll
        for (int i = 0; i < 8; ++i) {
            aw[i] *= inv;
            awacc[i] += aw[i];
            int k = 16 * (i >> 2) + 4 * g + (i & 3);
            aw_lds[k * SAH + 16 * w + nloc] = f2bf(aw[i]);
        }
        __syncthreads();

        // ---- matmul2: ENC[k][c] += AW^T · X^T over this tile's 64 n ----
        const int sh = (nloc & 1) * 16;
        #pragma unroll
        for (int ns = 0; ns < 2; ++ns) {
            bf16x8 afr[2];
            #pragma unroll
            for (int t = 0; t < 2; ++t)
                afr[t] = u4_frag(*(const uint4*)&aw_lds[(16*t + nloc) * SAH + ns*32 + g*8]);
            #pragma unroll
            for (int ct = 0; ct < 8; ++ct) {
                const int base = (64*w + 8*ct + (nloc >> 1)) * XROW + ns*32 + g*8;
                uint4 d0 = *(const uint4*)&x_cp[base];
                uint4 d1 = *(const uint4*)&x_cp[base + 4];
                unsigned int f0 = ((d0.x >> sh) & 0xffffu) | (((d0.y >> sh) & 0xffffu) << 16);
                unsigned int f1 = ((d0.z >> sh) & 0xffffu) | (((d0.w >> sh) & 0xffffu) << 16);
                unsigned int f2 = ((d1.x >> sh) & 0xffffu) | (((d1.y >> sh) & 0xffffu) << 16);
                unsigned int f3 = ((d1.z >> sh) & 0xffffu) | (((d1.w >> sh) & 0xffffu) << 16);
                bf16x8 bfr = u4_frag(make_uint4(f0, f1, f2, f3));
                acc2[0][ct] = __builtin_amdgcn_mfma_f32_16x16x32_bf16(afr[0], bfr, acc2[0][ct], 0,0,0);
                acc2[1][ct] = __builtin_amdgcn_mfma_f32_16x16x32_bf16(afr[1], bfr, acc2[1][ct], 0,0,0);
            }
        }
        // next iteration's __syncthreads() protects x_cp reuse
    }

    // ---- block awsum[k]: reduce over n (lanes nloc) then across waves ----
    #pragma unroll
    for (int i = 0; i < 8; ++i) {
        float v = awacc[i];
        v += __shfl_xor(v, 1);
        v += __shfl_xor(v, 2);
        v += __shfl_xor(v, 4);
        v += __shfl_xor(v, 8);
        awacc[i] = v;
    }
    if (nloc == 0) {
        #pragma unroll
        for (int i = 0; i < 8; ++i) {
            int k = 16 * (i >> 2) + 4 * g + (i & 3);
            atomicAdd(&awsum[k], awacc[i]);
        }
    }
    __syncthreads();

    // ---- epilogue: fold -awsum*cw, atomicAdd partials ----
    float* ob = out + (size_t)b * Kc * Cc;
    #pragma unroll
    for (int t = 0; t < 2; ++t)
        #pragma unroll
        for (int ct = 0; ct < 8; ++ct)
            #pragma unroll
            for (int r = 0; r < 4; ++r) {
                int k = 16 * t + 4 * g + r;
                int c = 128 * w + 16 * ct + nloc;
                float val = fmaf(-awsum[k], cw[k * Cc + c], acc2[t][ct][r]);
                atomicAdd(&ob[k * Cc + c], val);
            }
}

extern "C" void kernel_launch(void* const* d_in, const int* in_sizes, int n_in,
                              void* d_out, int out_size, void* d_ws, size_t ws_size,
                              hipStream_t stream) {
    const float* x     = (const float*)d_in[0];
    const float* cwp   = (const float*)d_in[1];
    const float* scale = (const float*)d_in[2];
    float* out = (float*)d_out;

    hipMemsetAsync(out, 0, (size_t)out_size * sizeof(float), stream);
    enc_mfma<<<dim3(256), dim3(256), 0, stream>>>(x, cwp, scale, out);
}